// Round 1
// baseline (643.157 us; speedup 1.0000x reference)
//
#include <hip/hip_runtime.h>

typedef unsigned short u16;
typedef __attribute__((ext_vector_type(8))) __bf16 bf16x8;
typedef __attribute__((ext_vector_type(4))) float f32x4;

#define IN_F 4096
#define OUT_F 4096
#define MDIM 8192
#define BM 128
#define BN 128
#define BK 32

// round-to-nearest-even fp32 -> bf16 (bit pattern)
__device__ __forceinline__ u16 f2bf(float f) {
  union { float f; unsigned int u; } v; v.f = f;
  unsigned int r = (v.u + 0x7fffu + ((v.u >> 16) & 1u)) >> 16;
  return (u16)r;
}

// Phase 1: W_bf16[o][i] = bf16(centroid[idx[o][i]]), 4 elems/thread
__global__ __launch_bounds__(256) void dequant_kernel(const int* __restrict__ idx,
                                                      const float* __restrict__ table,
                                                      u16* __restrict__ Wb) {
  __shared__ float cent[256];
  cent[threadIdx.x] = table[threadIdx.x];
  __syncthreads();
  size_t i = (size_t)blockIdx.x * 256 + threadIdx.x;
  int4 v = ((const int4*)idx)[i];
  ushort4 o;
  o.x = f2bf(cent[v.x]); o.y = f2bf(cent[v.y]);
  o.z = f2bf(cent[v.z]); o.w = f2bf(cent[v.w]);
  ((ushort4*)Wb)[i] = o;
}

// Phase 2: X fp32 -> bf16, 4 elems/thread
__global__ __launch_bounds__(256) void cvt_kernel(const float* __restrict__ X,
                                                  u16* __restrict__ Xb) {
  size_t i = (size_t)blockIdx.x * 256 + threadIdx.x;
  float4 v = ((const float4*)X)[i];
  ushort4 o;
  o.x = f2bf(v.x); o.y = f2bf(v.y); o.z = f2bf(v.z); o.w = f2bf(v.w);
  ((ushort4*)Xb)[i] = o;
}

// async global->LDS, 16B per lane; LDS dest is wave-uniform base + lane*16
__device__ __forceinline__ void gld_lds16(const u16* g, u16* l) {
  __builtin_amdgcn_global_load_lds((const __attribute__((address_space(1))) void*)g,
                                   (__attribute__((address_space(3))) void*)l,
                                   16, 0, 0);
}

// Phase 3: C[m][n] = sum_k Xb[m][k] * Wb[n][k]  (both K-major, "gemm_bt")
// 128x128 block tile, BK=32, 256 thr = 4 waves in 2x2, each wave 64x64 (4x4 MFMA tiles)
__global__ __launch_bounds__(256) void gemm_kernel(const u16* __restrict__ Xb,
                                                   const u16* __restrict__ Wb,
                                                   float* __restrict__ out) {
  __shared__ u16 As[BM * BK];  // [m][k], k contiguous, 8 KB
  __shared__ u16 Bs[BN * BK];  // [n][k], 8 KB
  const int tid = threadIdx.x;
  const int lane = tid & 63;
  const int wv = tid >> 6;
  const int bn = blockIdx.x;   // 0..31
  const int bm = blockIdx.y;   // 0..63
  const int wm = (wv >> 1) * 64;
  const int wn = (wv & 1) * 64;

  // staging: wave wv fills LDS chunks 2wv,2wv+1 (1KB each). lane i -> row chunk*16 + i/4,
  // k-chunk (i%4)*8. Global rows bm*128 + wv*32 + i/4 (+16 for 2nd inst).
  const int srow = wv * 32 + (lane >> 2);
  const int skoff = (lane & 3) * 8;
  const u16* gA = Xb + (size_t)(bm * BM + srow) * IN_F + skoff;
  const u16* gB = Wb + (size_t)(bn * BN + srow) * IN_F + skoff;
  u16* lA = As + wv * 1024;   // wave-uniform LDS base (elements)
  u16* lB = Bs + wv * 1024;

  // fragment bases: lane reads [row = lane&15][k = (lane>>4)*8 .. +8] (16B, ds_read_b128)
  const int kq = (lane >> 4) * 8;
  const u16* a0 = As + (wm + (lane & 15)) * BK + kq;
  const u16* b0 = Bs + (wn + (lane & 15)) * BK + kq;

  f32x4 acc[4][4] = {};

  for (int kt = 0; kt < IN_F / BK; ++kt) {
    gld_lds16(gA, lA);
    gld_lds16(gA + 16 * IN_F, lA + 512);
    gld_lds16(gB, lB);
    gld_lds16(gB + 16 * IN_F, lB + 512);
    gA += BK; gB += BK;
    __syncthreads();   // drains vmcnt(0): staged data visible

    bf16x8 a[4], b[4];
#pragma unroll
    for (int i = 0; i < 4; ++i) a[i] = *(const bf16x8*)(a0 + i * 16 * BK);
#pragma unroll
    for (int i = 0; i < 4; ++i) b[i] = *(const bf16x8*)(b0 + i * 16 * BK);
#pragma unroll
    for (int mi = 0; mi < 4; ++mi)
#pragma unroll
      for (int ni = 0; ni < 4; ++ni)
        acc[mi][ni] = __builtin_amdgcn_mfma_f32_16x16x32_bf16(a[mi], b[ni], acc[mi][ni], 0, 0, 0);
    __syncthreads();   // all reads done before next iteration overwrites LDS
  }

  // C/D layout (m89-verified): col = lane&15, row = (lane>>4)*4 + reg
  const int col = lane & 15;
  const int quad = lane >> 4;
#pragma unroll
  for (int mi = 0; mi < 4; ++mi)
#pragma unroll
    for (int r = 0; r < 4; ++r) {
      int m = bm * BM + wm + mi * 16 + quad * 4 + r;
      float* op = out + (size_t)m * OUT_F + bn * BN + wn + col;
#pragma unroll
      for (int ni = 0; ni < 4; ++ni)
        op[ni * 16] = acc[mi][ni][r];
    }
}

extern "C" void kernel_launch(void* const* d_in, const int* in_sizes, int n_in,
                              void* d_out, int out_size, void* d_ws, size_t ws_size,
                              hipStream_t stream) {
  const float* X = (const float*)d_in[0];       // [4,2048,4096] fp32
  const float* table = (const float*)d_in[1];   // [256,1] fp32
  const int* idx = (const int*)d_in[2];         // [4096,4096] int32
  float* out = (float*)d_out;                   // [4,2048,4096] fp32

  u16* Wb = (u16*)d_ws;                         // 32 MiB bf16 weights [OUT_F][IN_F]
  u16* Xb = Wb + (size_t)OUT_F * IN_F;          // 64 MiB bf16 input  [MDIM][IN_F]

  dequant_kernel<<<(OUT_F * IN_F) / (4 * 256), 256, 0, stream>>>(idx, table, Wb);
  cvt_kernel<<<(MDIM * IN_F) / (4 * 256), 256, 0, stream>>>(X, Xb);
  dim3 grid(OUT_F / BN, MDIM / BM);             // (32, 64)
  gemm_kernel<<<grid, 256, 0, stream>>>(Xb, Wb, out);
}

// Round 2
// 630.456 us; speedup vs baseline: 1.0201x; 1.0201x over previous
//
#include <hip/hip_runtime.h>

typedef unsigned short u16;
typedef __attribute__((ext_vector_type(8))) __bf16 bf16x8;
typedef __attribute__((ext_vector_type(4))) float f32x4;

#define IN_F 4096
#define OUT_F 4096
#define MDIM 8192
#define BM 128
#define BN 128
#define BK 32

// round-to-nearest-even fp32 -> bf16 (bit pattern)
__device__ __forceinline__ u16 f2bf(float f) {
  union { float f; unsigned int u; } v; v.f = f;
  unsigned int r = (v.u + 0x7fffu + ((v.u >> 16) & 1u)) >> 16;
  return (u16)r;
}

#define DQ_BLOCKS (OUT_F * IN_F / (4 * 256))   // 16384
#define CV_BLOCKS (MDIM * IN_F / (4 * 256))    // 32768

// Merged pre-pass: blocks [0, DQ_BLOCKS) dequant W; rest convert X.
__global__ __launch_bounds__(256) void prep_kernel(const int* __restrict__ idx,
                                                   const float* __restrict__ table,
                                                   const float* __restrict__ X,
                                                   u16* __restrict__ Wb,
                                                   u16* __restrict__ Xb) {
  int b = blockIdx.x;
  if (b < DQ_BLOCKS) {
    __shared__ float cent[256];
    cent[threadIdx.x] = table[threadIdx.x];
    __syncthreads();
    size_t i = (size_t)b * 256 + threadIdx.x;
    int4 v = ((const int4*)idx)[i];
    ushort4 o;
    o.x = f2bf(cent[v.x]); o.y = f2bf(cent[v.y]);
    o.z = f2bf(cent[v.z]); o.w = f2bf(cent[v.w]);
    ((ushort4*)Wb)[i] = o;
  } else {
    size_t i = (size_t)(b - DQ_BLOCKS) * 256 + threadIdx.x;
    float4 v = ((const float4*)X)[i];
    ushort4 o;
    o.x = f2bf(v.x); o.y = f2bf(v.y); o.z = f2bf(v.z); o.w = f2bf(v.w);
    ((ushort4*)Xb)[i] = o;
  }
}

// async global->LDS, 16B per lane; LDS dest is wave-uniform base + lane*16
__device__ __forceinline__ void gld_lds16(const u16* g, u16* l) {
  __builtin_amdgcn_global_load_lds((const __attribute__((address_space(1))) void*)g,
                                   (__attribute__((address_space(3))) void*)l,
                                   16, 0, 0);
}

// C[m][n] = sum_k Xb[m][k] * Wb[n][k]  (both K-major)
// 128x128 block tile, BK=32, 4 waves 2x2, wave tile 64x64 (4x4 MFMA 16x16x32).
// LDS layout swizzled to kill ds_read_b128 bank conflicts:
//   data (row R, 16B-chunk c) lives at slot (c + (R>>1)) & 3 within R's 64B row.
__global__ __launch_bounds__(256) void gemm_kernel(const u16* __restrict__ Xb,
                                                   const u16* __restrict__ Wb,
                                                   float* __restrict__ out) {
  __shared__ u16 As[BM * BK];  // 8 KB
  __shared__ u16 Bs[BN * BK];  // 8 KB
  const int tid = threadIdx.x;
  const int lane = tid & 63;
  const int wv = tid >> 6;
  const int bn = blockIdx.x;   // 0..31
  const int bm = blockIdx.y;   // 0..63
  const int wm = (wv >> 1) * 64;
  const int wn = (wv & 1) * 64;

  // Staging: wave wv fills rows wv*32..+15 (inst 1) and +16..+31 (inst 2).
  // Lane i writes LDS slot i (16B) = row i>>2, slot-pos i&3. With the swizzle,
  // the chunk to load there is c = ((i&3) - ((i>>3)&3)) & 3  (same for both insts:
  // +16 rows shifts R>>1 by 8 == 0 mod 4).
  const int srow = wv * 32 + (lane >> 2);
  const int schunk = ((lane & 3) - ((lane >> 3) & 3)) & 3;
  const int skoff = schunk * 8;
  const u16* gA = Xb + (size_t)(bm * BM + srow) * IN_F + skoff;
  const u16* gB = Wb + (size_t)(bn * BN + srow) * IN_F + skoff;
  u16* lA = As + wv * 1024;   // wave-uniform LDS base (elements)
  u16* lB = Bs + wv * 1024;

  // Fragment read: lane wants row (lane&15)+tile-offset, chunk q=lane>>4.
  // Swizzled slot = (q + ((lane&15)>>1)) & 3  (tile offsets wm, mi*16 are 0 mod 4
  // in R>>1, so per-lane constant). Bank-group pattern per quad: 0,4,1,5,2,6,3,7
  // twice -> 2-way only (free).
  const int rslot = ((lane >> 4) + ((lane & 15) >> 1)) & 3;
  const u16* a0 = As + (wm + (lane & 15)) * BK + rslot * 8;
  const u16* b0 = Bs + (wn + (lane & 15)) * BK + rslot * 8;

  f32x4 acc[4][4] = {};

  for (int kt = 0; kt < IN_F / BK; ++kt) {
    gld_lds16(gA, lA);
    gld_lds16(gA + 16 * IN_F, lA + 512);
    gld_lds16(gB, lB);
    gld_lds16(gB + 16 * IN_F, lB + 512);
    gA += BK; gB += BK;
    __syncthreads();   // drains vmcnt(0): staged data visible

    bf16x8 a[4], b[4];
#pragma unroll
    for (int i = 0; i < 4; ++i) a[i] = *(const bf16x8*)(a0 + i * 16 * BK);
#pragma unroll
    for (int i = 0; i < 4; ++i) b[i] = *(const bf16x8*)(b0 + i * 16 * BK);
#pragma unroll
    for (int mi = 0; mi < 4; ++mi)
#pragma unroll
      for (int ni = 0; ni < 4; ++ni)
        acc[mi][ni] = __builtin_amdgcn_mfma_f32_16x16x32_bf16(a[mi], b[ni], acc[mi][ni], 0, 0, 0);
    __syncthreads();   // all reads done before next iteration overwrites LDS
  }

  // C/D layout (m89-verified): col = lane&15, row = (lane>>4)*4 + reg
  const int col = lane & 15;
  const int quad = lane >> 4;
#pragma unroll
  for (int mi = 0; mi < 4; ++mi)
#pragma unroll
    for (int r = 0; r < 4; ++r) {
      int m = bm * BM + wm + mi * 16 + quad * 4 + r;
      float* op = out + (size_t)m * OUT_F + bn * BN + wn + col;
#pragma unroll
      for (int ni = 0; ni < 4; ++ni)
        op[ni * 16] = acc[mi][ni][r];
    }
}

extern "C" void kernel_launch(void* const* d_in, const int* in_sizes, int n_in,
                              void* d_out, int out_size, void* d_ws, size_t ws_size,
                              hipStream_t stream) {
  const float* X = (const float*)d_in[0];       // [4,2048,4096] fp32
  const float* table = (const float*)d_in[1];   // [256,1] fp32
  const int* idx = (const int*)d_in[2];         // [4096,4096] int32
  float* out = (float*)d_out;                   // [4,2048,4096] fp32

  u16* Wb = (u16*)d_ws;                         // 32 MiB bf16 weights [OUT_F][IN_F]
  u16* Xb = Wb + (size_t)OUT_F * IN_F;          // 64 MiB bf16 input  [MDIM][IN_F]

  prep_kernel<<<DQ_BLOCKS + CV_BLOCKS, 256, 0, stream>>>(idx, table, X, Wb, Xb);
  dim3 grid(OUT_F / BN, MDIM / BM);             // (32, 64)
  gemm_kernel<<<grid, 256, 0, stream>>>(Xb, Wb, out);
}

// Round 3
// 594.068 us; speedup vs baseline: 1.0826x; 1.0613x over previous
//
#include <hip/hip_runtime.h>

typedef unsigned short u16;
typedef __attribute__((ext_vector_type(8))) __bf16 bf16x8;
typedef __attribute__((ext_vector_type(4))) float f32x4;
typedef __attribute__((ext_vector_type(4))) int i32x4;
typedef __attribute__((ext_vector_type(8))) unsigned short u16x8;

#define IN_F 4096
#define OUT_F 4096
#define MDIM 8192
#define BM 128
#define BN 128
#define BK 32
#define NK (IN_F / BK)

// round-to-nearest-even fp32 -> bf16 (bit pattern)
__device__ __forceinline__ u16 f2bf(float f) {
  union { float f; unsigned int u; } v; v.f = f;
  unsigned int r = (v.u + 0x7fffu + ((v.u >> 16) & 1u)) >> 16;
  return (u16)r;
}

#define DQ_BLOCKS (OUT_F * IN_F / (8 * 256))   // 8192
#define CV_BLOCKS (MDIM * IN_F / (8 * 256))    // 16384

// Merged pre-pass, 8 elems/thread. nt loads: idx and X are read exactly once.
// Wb/Xb stores stay cached (gemm re-reads them).
__global__ __launch_bounds__(256) void prep_kernel(const int* __restrict__ idx,
                                                   const float* __restrict__ table,
                                                   const float* __restrict__ X,
                                                   u16* __restrict__ Wb,
                                                   u16* __restrict__ Xb) {
  int b = blockIdx.x;
  if (b < DQ_BLOCKS) {
    __shared__ float cent[256];
    cent[threadIdx.x] = table[threadIdx.x];
    __syncthreads();
    size_t i = (size_t)b * 256 + threadIdx.x;        // units of 8 elems
    const i32x4* p = (const i32x4*)idx + 2 * i;
    i32x4 v0 = __builtin_nontemporal_load(p);
    i32x4 v1 = __builtin_nontemporal_load(p + 1);
    u16x8 o;
    o[0] = f2bf(cent[v0[0]]); o[1] = f2bf(cent[v0[1]]);
    o[2] = f2bf(cent[v0[2]]); o[3] = f2bf(cent[v0[3]]);
    o[4] = f2bf(cent[v1[0]]); o[5] = f2bf(cent[v1[1]]);
    o[6] = f2bf(cent[v1[2]]); o[7] = f2bf(cent[v1[3]]);
    ((u16x8*)Wb)[i] = o;
  } else {
    size_t i = (size_t)(b - DQ_BLOCKS) * 256 + threadIdx.x;
    const f32x4* p = (const f32x4*)X + 2 * i;
    f32x4 v0 = __builtin_nontemporal_load(p);
    f32x4 v1 = __builtin_nontemporal_load(p + 1);
    u16x8 o;
    o[0] = f2bf(v0[0]); o[1] = f2bf(v0[1]); o[2] = f2bf(v0[2]); o[3] = f2bf(v0[3]);
    o[4] = f2bf(v1[0]); o[5] = f2bf(v1[1]); o[6] = f2bf(v1[2]); o[7] = f2bf(v1[3]);
    ((u16x8*)Xb)[i] = o;
  }
}

// async global->LDS, 16B per lane; LDS dest is wave-uniform base + lane*16
__device__ __forceinline__ void gld_lds16(const u16* g, u16* l) {
  __builtin_amdgcn_global_load_lds((const __attribute__((address_space(1))) void*)g,
                                   (__attribute__((address_space(3))) void*)l,
                                   16, 0, 0);
}

// C[m][n] = sum_k Xb[m][k] * Wb[n][k]  (both K-major)
// 128x128 block tile, BK=32, 4 waves 2x2, wave tile 64x64 (4x4 MFMA 16x16x32).
// LDS double-buffered: ONE barrier per kt; stage k+1 right after the barrier so
// its vmcnt(0) drain (compiler-emitted before next s_barrier) lands a full
// MFMA phase after issue.
// Swizzle (r2-verified, 0 conflicts): chunk c of row R lives at slot (c+(R>>1))&3.
__global__ __launch_bounds__(256) void gemm_kernel(const u16* __restrict__ Xb,
                                                   const u16* __restrict__ Wb,
                                                   float* __restrict__ out) {
  __shared__ u16 As[2][BM * BK];  // 2 x 8 KB
  __shared__ u16 Bs[2][BN * BK];  // 2 x 8 KB
  const int tid = threadIdx.x;
  const int lane = tid & 63;
  const int wv = tid >> 6;
  const int bn = blockIdx.x;   // 0..31
  const int bm = blockIdx.y;   // 0..63
  const int wm = (wv >> 1) * 64;
  const int wn = (wv & 1) * 64;

  // Staging: wave wv fills rows wv*32..+15 (inst 1), +16..+31 (inst 2).
  // Lane i -> row i>>2, slot i&3; chunk c = ((i&3) - ((i>>3)&3)) & 3.
  const int srow = wv * 32 + (lane >> 2);
  const int schunk = ((lane & 3) - ((lane >> 3) & 3)) & 3;
  const int skoff = schunk * 8;
  const u16* gA = Xb + (size_t)(bm * BM + srow) * IN_F + skoff;
  const u16* gB = Wb + (size_t)(bn * BN + srow) * IN_F + skoff;
  const int stoff = wv * 1024;   // wave-uniform LDS base (elements)

  // Fragment read: slot = ((lane>>4) + ((lane&15)>>1)) & 3; 2 lanes/bank -> free.
  const int rslot = ((lane >> 4) + ((lane & 15) >> 1)) & 3;
  const int aoff = (wm + (lane & 15)) * BK + rslot * 8;
  const int boff = (wn + (lane & 15)) * BK + rslot * 8;

  // Prologue: stage tile 0 into buffer 0.
  gld_lds16(gA, As[0] + stoff);
  gld_lds16(gA + 16 * IN_F, As[0] + stoff + 512);
  gld_lds16(gB, Bs[0] + stoff);
  gld_lds16(gB + 16 * IN_F, Bs[0] + stoff + 512);
  gA += BK; gB += BK;

  f32x4 acc[4][4] = {};

  for (int kt = 0; kt < NK; ++kt) {
    __syncthreads();   // drains vmcnt: tile kt staged; prior reads of other buf done
    if (kt + 1 < NK) {
      u16* nA = (u16*)As[(kt + 1) & 1] + stoff;
      u16* nB = (u16*)Bs[(kt + 1) & 1] + stoff;
      gld_lds16(gA, nA);
      gld_lds16(gA + 16 * IN_F, nA + 512);
      gld_lds16(gB, nB);
      gld_lds16(gB + 16 * IN_F, nB + 512);
      gA += BK; gB += BK;
    }
    const u16* a0 = (const u16*)As[kt & 1] + aoff;
    const u16* b0 = (const u16*)Bs[kt & 1] + boff;
    bf16x8 a[4], b[4];
#pragma unroll
    for (int i = 0; i < 4; ++i) a[i] = *(const bf16x8*)(a0 + i * 16 * BK);
#pragma unroll
    for (int i = 0; i < 4; ++i) b[i] = *(const bf16x8*)(b0 + i * 16 * BK);
#pragma unroll
    for (int mi = 0; mi < 4; ++mi)
#pragma unroll
      for (int ni = 0; ni < 4; ++ni)
        acc[mi][ni] = __builtin_amdgcn_mfma_f32_16x16x32_bf16(a[mi], b[ni], acc[mi][ni], 0, 0, 0);
  }

  // C/D layout (m89-verified): col = lane&15, row = (lane>>4)*4 + reg.
  // Non-temporal: d_out is write-once, never re-read -> don't evict Xb/Wb from LLC.
  const int col = lane & 15;
  const int quad = lane >> 4;
#pragma unroll
  for (int mi = 0; mi < 4; ++mi)
#pragma unroll
    for (int r = 0; r < 4; ++r) {
      int m = bm * BM + wm + mi * 16 + quad * 4 + r;
      float* op = out + (size_t)m * OUT_F + bn * BN + wn + col;
#pragma unroll
      for (int ni = 0; ni < 4; ++ni)
        __builtin_nontemporal_store(acc[mi][ni][r], op + ni * 16);
    }
}

extern "C" void kernel_launch(void* const* d_in, const int* in_sizes, int n_in,
                              void* d_out, int out_size, void* d_ws, size_t ws_size,
                              hipStream_t stream) {
  const float* X = (const float*)d_in[0];       // [4,2048,4096] fp32
  const float* table = (const float*)d_in[1];   // [256,1] fp32
  const int* idx = (const int*)d_in[2];         // [4096,4096] int32
  float* out = (float*)d_out;                   // [4,2048,4096] fp32

  u16* Wb = (u16*)d_ws;                         // 32 MiB bf16 weights [OUT_F][IN_F]
  u16* Xb = Wb + (size_t)OUT_F * IN_F;          // 64 MiB bf16 input  [MDIM][IN_F]

  prep_kernel<<<DQ_BLOCKS + CV_BLOCKS, 256, 0, stream>>>(idx, table, X, Wb, Xb);
  dim3 grid(OUT_F / BN, MDIM / BM);             // (32, 64)
  gemm_kernel<<<grid, 256, 0, stream>>>(Xb, Wb, out);
}